// Round 3
// baseline (241.500 us; speedup 1.0000x reference)
//
#include <hip/hip_runtime.h>

// KGL: per-patch kernel generation.
//  x: (8, 768, 768, 9) fp32. PSZ=24 -> p1=p2=32, N=1024, N*B=8192 patches.
//  Patch flat index j = b*1024 + pi*32 + pj (raw-reshape preserves buffer order).
//  out[0 .. 663551]        = wg1: conv3x3 stride8 (pad=0 -> 3x3) clipped per-oc over spatial
//  out[663552 .. 1327103]  = wg2: (GAP @ dense_w + b) as 9x9, clipped per-column over rows
//
// R3 structure: conv reads its 729 patch floats straight from global (L1/L2 hits on
// the same lines the DMA stages), each conv wave stages its own conv_w copy
// (wave-local, no barrier). Patch DMA (waves 2-3) feeds only the GAP path.

#define PSZ 24
#define NCH 9
#define HW 768
#define PATCH_ELEMS (PSZ*PSZ*NCH)   // 5184 floats = 1296 float4
#define PATCH_V4 1296
#define NPIX (PSZ*PSZ)              // 576
#define ROWF (PSZ*NCH)              // 216 floats per patch row (54 float4, 16B-aligned)
#define ROWV4 54
#define XROWF (HW*NCH)              // 6912 floats per image row
#define OUT2_OFF 663552

__device__ inline void async_load16(const void* g, void* l) {
    __builtin_amdgcn_global_load_lds(
        (const __attribute__((address_space(1))) void*)g,
        (__attribute__((address_space(3))) void*)l, 16, 0, 0);
}

__global__ __launch_bounds__(256) void kgl_kernel(
    const float* __restrict__ x,
    const float* __restrict__ conv_w,   // (3,3,9,9) HWIO flat, 729
    const float* __restrict__ conv_b,   // (9,)
    const float* __restrict__ dense_w,  // (9,81)
    const float* __restrict__ dense_b,  // (81,)
    float* __restrict__ out)
{
    __shared__ __align__(16) float patch[PATCH_ELEMS];
    __shared__ __align__(16) float cwA[732];   // wave0's copy (729 used)
    __shared__ __align__(16) float cwB[732];   // wave1's copy
    __shared__ __align__(16) float colA[ROWF]; // column sums rows 0..11 (wave2)
    __shared__ __align__(16) float colB[ROWF]; // column sums rows 12..23 (wave3)
    __shared__ float gapA[NCH];
    __shared__ float gapB[NCH];
    __shared__ float co_s[81];
    __shared__ float d_s[81];

    const int j   = blockIdx.x;
    const int b   = j >> 10;
    const int rem = j & 1023;
    const int pi  = rem >> 5;
    const int pj  = rem & 31;
    const int tid = threadIdx.x;

    const size_t base = ((size_t)(b*HW + pi*PSZ) * HW + (size_t)pj*PSZ) * NCH;

    float conv_acc = 0.f;

    // ---- Phase A ----
    if (tid < 128) {
        // Each conv wave stages its OWN conv_w copy -> wave-local, no barrier needed.
        float* cw = (tid < 64) ? cwA : cwB;
        const int lane = tid & 63;
        #pragma unroll
        for (int i = 0; i < 3; ++i) {
            int e = lane + i*64;
            if (e < 182)
                reinterpret_cast<float4*>(cw)[e] =
                    reinterpret_cast<const float4*>(conv_w)[e];
        }
        if (lane == 0) cw[728] = conv_w[728];

        if (tid < 81) {
            const int oy = tid / 27;
            const int ox = (tid / 9) % 3;
            const int oc = tid % 9;
            float acc = conv_b[oc];
            #pragma unroll
            for (int ky = 0; ky < 3; ++ky) {
                // 27 contiguous floats, 16B-aligned (row base is multiple of 16B)
                const float* gp = x + base + (size_t)(oy*8+ky)*XROWF + (size_t)(ox*8)*NCH;
                const float4* gp4 = reinterpret_cast<const float4*>(gp);
                float pv[27];
                #pragma unroll
                for (int q = 0; q < 6; ++q) {
                    float4 v = gp4[q];
                    pv[q*4+0] = v.x; pv[q*4+1] = v.y; pv[q*4+2] = v.z; pv[q*4+3] = v.w;
                }
                pv[24] = gp[24]; pv[25] = gp[25]; pv[26] = gp[26];
                #pragma unroll
                for (int kx = 0; kx < 3; ++kx) {
                    #pragma unroll
                    for (int ic = 0; ic < 9; ++ic)
                        acc += pv[kx*9+ic] * cw[(ky*3+kx)*81 + ic*9 + oc];
                }
            }
            co_s[tid] = acc;
            conv_acc = acc;
        }
    } else {
        // Waves 2-3: DMA the whole patch into LDS for the GAP path.
        const float* gbase = x + base;
        #pragma unroll
        for (int it = 0; it < 11; ++it) {
            int e4 = (tid - 128) + it*128;
            if (e4 < PATCH_V4) {
                int r = e4 / ROWV4;
                int t = e4 - r*ROWV4;
                async_load16(gbase + (size_t)r*XROWF + t*4, &patch[e4*4]);
            }
        }
    }
    __syncthreads();  // patch + co_s valid

    // ---- Phase B: wg1 clip+write (lanes 0..80); GAP colsums+fold (waves 2-3) ----
    if (tid < 81) {
        const int oc = tid % 9;
        float n2 = 0.f;
        #pragma unroll
        for (int s = 0; s < 9; ++s) {
            float v = co_s[s*9 + oc];
            n2 += v*v;
        }
        float sc = 1.0f / fmaxf(sqrtf(n2), 1.0f);
        out[(size_t)j*81 + tid] = conv_acc * sc;
    } else if (tid >= 128) {
        const int w  = (tid >= 192) ? 1 : 0;
        const int k  = tid & 63;
        float* col   = w ? colB : colA;
        const int r0 = w ? 12 : 0;
        if (k < ROWV4) {
            const float4* pv = reinterpret_cast<const float4*>(patch);
            float4 acc = pv[r0*ROWV4 + k];
            #pragma unroll
            for (int r = 1; r < 12; ++r) {
                float4 v = pv[(r0+r)*ROWV4 + k];
                acc.x += v.x; acc.y += v.y; acc.z += v.z; acc.w += v.w;
            }
            reinterpret_cast<float4*>(col)[k] = acc;
        }
        // wave-local fold: col written by this wave's own lanes
        if (k < NCH) {
            float s = 0.f;
            #pragma unroll
            for (int i = 0; i < 24; ++i) s += col[k + NCH*i];
            if (w) gapB[k] = s; else gapA[k] = s;
        }
    }
    __syncthreads();  // gapA/gapB valid

    // ---- Phase D: dense ----
    if (tid < 81) {
        float d = dense_b[tid];
        #pragma unroll
        for (int c = 0; c < NCH; ++c)
            d += (gapA[c] + gapB[c]) * (1.0f/(float)NPIX) * dense_w[c*81 + tid];
        d_s[tid] = d;
    }
    __syncthreads();  // d_s valid

    // ---- Phase E: wg2 clip+write ----
    if (tid < 81) {
        const int bc = tid % 9;
        float n2 = 0.f;
        #pragma unroll
        for (int a = 0; a < 9; ++a) {
            float v = d_s[a*9 + bc];
            n2 += v*v;
        }
        float sc = 1.0f / fmaxf(sqrtf(n2), 1.0f);
        out[OUT2_OFF + (size_t)j*81 + tid] = d_s[tid] * sc;
    }
}

extern "C" void kernel_launch(void* const* d_in, const int* in_sizes, int n_in,
                              void* d_out, int out_size, void* d_ws, size_t ws_size,
                              hipStream_t stream) {
    const float* x       = (const float*)d_in[0];
    const float* conv_w  = (const float*)d_in[1];
    const float* conv_b  = (const float*)d_in[2];
    const float* dense_w = (const float*)d_in[3];
    const float* dense_b = (const float*)d_in[4];
    float* out = (float*)d_out;

    kgl_kernel<<<8192, 256, 0, stream>>>(x, conv_w, conv_b, dense_w, dense_b, out);
}

// Round 4
// 239.055 us; speedup vs baseline: 1.0102x; 1.0102x over previous
//
#include <hip/hip_runtime.h>

// KGL: per-patch kernel generation.
//  x: (8, 768, 768, 9) fp32. PSZ=24 -> p1=p2=32, N=1024, N*B=8192 patches.
//  Patch flat index j = b*1024 + pi*32 + pj (raw-reshape preserves buffer order).
//  out[0 .. 663551]        = wg1: conv3x3 stride8 (pad=0 -> 3x3) clipped per-oc over spatial
//  out[663552 .. 1327103]  = wg2: (GAP @ dense_w + b) as 9x9, clipped per-column over rows
//
// R4: NO patch LDS staging. GAP accumulates straight from global (coalesced
// 864B row loads, 12 independent float4 loads in flight per lane); conv reads
// its 729 floats from global (L1/L2 hits on the same lines). LDS ~8KB ->
// 8 blocks/CU (wave-capped), 2 barriers.

#define PSZ 24
#define NCH 9
#define HW 768
#define NPIX (PSZ*PSZ)              // 576
#define ROWF (PSZ*NCH)              // 216 floats per patch row (54 float4, 16B-aligned)
#define ROWV4 54
#define XROWF (HW*NCH)              // 6912 floats per image row
#define OUT2_OFF 663552

__global__ __launch_bounds__(256) void kgl_kernel(
    const float* __restrict__ x,
    const float* __restrict__ conv_w,   // (3,3,9,9) HWIO flat, 729
    const float* __restrict__ conv_b,   // (9,)
    const float* __restrict__ dense_w,  // (9,81)
    const float* __restrict__ dense_b,  // (81,)
    float* __restrict__ out)
{
    __shared__ __align__(16) float cwA[732];   // wave0's copy (729 used)
    __shared__ __align__(16) float cwB[732];   // wave1's copy
    __shared__ __align__(16) float colA[ROWF]; // col sums rows 0..11  (wave2)
    __shared__ __align__(16) float colB[ROWF]; // col sums rows 12..23 (wave3)
    __shared__ float gapA[NCH];
    __shared__ float gapB[NCH];
    __shared__ float co_s[81];
    __shared__ float d_s[81];

    const int j   = blockIdx.x;
    const int b   = j >> 10;
    const int rem = j & 1023;
    const int pi  = rem >> 5;
    const int pj  = rem & 31;
    const int tid = threadIdx.x;

    const size_t base = ((size_t)(b*HW + pi*PSZ) * HW + (size_t)pj*PSZ) * NCH;
    const float* gbase = x + base;

    float conv_acc = 0.f;

    // ---- Phase A (no barrier inside) ----
    if (tid < 128) {
        // conv waves: wave-local conv_w copy (no barrier needed before use)
        float* cw = (tid < 64) ? cwA : cwB;
        const int lane = tid & 63;
        #pragma unroll
        for (int i = 0; i < 3; ++i) {
            int e = lane + i*64;
            if (e < 182)
                reinterpret_cast<float4*>(cw)[e] =
                    reinterpret_cast<const float4*>(conv_w)[e];
        }
        if (lane == 0) cw[728] = conv_w[728];

        if (tid < 81) {
            const int oy = tid / 27;
            const int ox = (tid / 9) % 3;
            const int oc = tid % 9;
            float acc = conv_b[oc];
            #pragma unroll
            for (int ky = 0; ky < 3; ++ky) {
                // 27 needed floats; load 7 aligned float4 (28), last lane ignored.
                const float* gp = gbase + (size_t)(oy*8+ky)*XROWF + (size_t)(ox*8)*NCH;
                const float4* gp4 = reinterpret_cast<const float4*>(gp);
                float pv[28];
                #pragma unroll
                for (int q = 0; q < 7; ++q) {
                    float4 v = gp4[q];
                    pv[q*4+0] = v.x; pv[q*4+1] = v.y; pv[q*4+2] = v.z; pv[q*4+3] = v.w;
                }
                #pragma unroll
                for (int kx = 0; kx < 3; ++kx) {
                    #pragma unroll
                    for (int ic = 0; ic < 9; ++ic)
                        acc += pv[kx*9+ic] * cw[(ky*3+kx)*81 + ic*9 + oc];
                }
            }
            co_s[tid] = acc;
            conv_acc = acc;
        }
    } else {
        // GAP waves: accumulate column sums straight from global.
        const int w  = (tid >= 192) ? 1 : 0;
        const int k  = tid & 63;
        const int r0 = w ? 12 : 0;
        if (k < ROWV4) {
            float4 acc = make_float4(0.f, 0.f, 0.f, 0.f);
            #pragma unroll
            for (int r = 0; r < 12; ++r) {
                float4 v = *reinterpret_cast<const float4*>(
                    gbase + (size_t)(r0 + r)*XROWF + (size_t)k*4);
                acc.x += v.x; acc.y += v.y; acc.z += v.z; acc.w += v.w;
            }
            reinterpret_cast<float4*>(w ? colB : colA)[k] = acc;
        }
        // wave-local fold 216 -> 9 channels
        if (k < NCH) {
            const float* col = w ? colB : colA;
            float s = 0.f;
            #pragma unroll
            for (int i = 0; i < 24; ++i) s += col[k + NCH*i];
            if (w) gapB[k] = s; else gapA[k] = s;
        }
    }
    __syncthreads();  // co_s, gapA, gapB valid

    // ---- Phase B: wg1 clip+write; dense ----
    if (tid < 81) {
        const int oc = tid % 9;
        float n2 = 0.f;
        #pragma unroll
        for (int s = 0; s < 9; ++s) {
            float v = co_s[s*9 + oc];
            n2 += v*v;
        }
        float sc = 1.0f / fmaxf(sqrtf(n2), 1.0f);
        out[(size_t)j*81 + tid] = conv_acc * sc;

        float d = dense_b[tid];
        #pragma unroll
        for (int c = 0; c < NCH; ++c)
            d += (gapA[c] + gapB[c]) * (1.0f/(float)NPIX) * dense_w[c*81 + tid];
        d_s[tid] = d;
    }
    __syncthreads();  // d_s valid

    // ---- Phase C: wg2 clip+write ----
    if (tid < 81) {
        const int bc = tid % 9;
        float n2 = 0.f;
        #pragma unroll
        for (int a = 0; a < 9; ++a) {
            float v = d_s[a*9 + bc];
            n2 += v*v;
        }
        float sc = 1.0f / fmaxf(sqrtf(n2), 1.0f);
        out[OUT2_OFF + (size_t)j*81 + tid] = d_s[tid] * sc;
    }
}

extern "C" void kernel_launch(void* const* d_in, const int* in_sizes, int n_in,
                              void* d_out, int out_size, void* d_ws, size_t ws_size,
                              hipStream_t stream) {
    const float* x       = (const float*)d_in[0];
    const float* conv_w  = (const float*)d_in[1];
    const float* conv_b  = (const float*)d_in[2];
    const float* dense_w = (const float*)d_in[3];
    const float* dense_b = (const float*)d_in[4];
    float* out = (float*)d_out;

    kgl_kernel<<<8192, 256, 0, stream>>>(x, conv_w, conv_b, dense_w, dense_b, out);
}